// Round 9
// baseline (134.870 us; speedup 1.0000x reference)
//
#include <hip/hip_runtime.h>

#define DEV __device__ __forceinline__

typedef _Float16 f16x8 __attribute__((ext_vector_type(8)));
typedef _Float16 f16x4 __attribute__((ext_vector_type(4)));
typedef float f32x4 __attribute__((ext_vector_type(4)));
typedef float f32x16 __attribute__((ext_vector_type(16)));
typedef unsigned int u32x4 __attribute__((ext_vector_type(4)));
typedef unsigned int u32x2 __attribute__((ext_vector_type(2)));

// async global->LDS, 16B per lane. LDS dest must be wave-uniform base (+lane*16 in HW).
DEV void glds16(const void* g, void* l) {
    __builtin_amdgcn_global_load_lds(
        (const __attribute__((address_space(1))) void*)g,
        (__attribute__((address_space(3))) void*)l, 16, 0, 0);
}

DEV unsigned pkh(float lo, float hi) {
    return __builtin_bit_cast(unsigned, __builtin_amdgcn_cvt_pkrtz(lo, hi));
}

// ---------------------------------------------------------------------------
// cast fp32 -> fp16, 4 elems/thread
__global__ __launch_bounds__(256) void cast_f32_f16(const float* __restrict__ src,
                                                    _Float16* __restrict__ dst, int n4) {
    const int i = blockIdx.x * 256 + threadIdx.x;
    if (i >= n4) return;
    const float4 v = ((const float4*)src)[i];
    f16x4 o = { (_Float16)v.x, (_Float16)v.y, (_Float16)v.z, (_Float16)v.w };
    *(f16x4*)(dst + (size_t)i * 4) = o;
}

// ---------------------------------------------------------------------------
// Fold LoRA (I + A B) into Q/V sections of Wqkv; fold softmax scale AND log2(e)
// into Q (attention uses exp2-domain softmax). grid (24, 3): no c-loop.
__global__ __launch_bounds__(256) void prep_w(const float* __restrict__ W,
                                              const float* __restrict__ Aq,
                                              const float* __restrict__ Bq,
                                              const float* __restrict__ Av,
                                              const float* __restrict__ Bv,
                                              _Float16* __restrict__ Wb) {
    const int bx = blockIdx.x;         // 0..23: 12 Q heads then 12 V heads
    const int sec = bx / 12;           // 0 = Q, 1 = V
    const int h = bx - sec * 12;
    const float* Am = sec ? Av : Aq;   // [64][4]
    const float* Bm = sec ? Bv : Bq;   // [4][64]
    const int base = sec ? (1536 + h * 64) : (h * 64);
    const float scale = sec ? 1.0f : (0.125f * 1.4426950408889634f);
    const int c = blockIdx.y * 256 + threadIdx.x;
    float t0 = 0.f, t1 = 0.f, t2 = 0.f, t3 = 0.f;
    for (int j = 0; j < 64; ++j) {
        const float w = W[(size_t)(base + j) * 768 + c];
        t0 += Am[j * 4 + 0] * w;
        t1 += Am[j * 4 + 1] * w;
        t2 += Am[j * 4 + 2] * w;
        t3 += Am[j * 4 + 3] * w;
    }
    for (int i = 0; i < 64; ++i) {
        const float w = W[(size_t)(base + i) * 768 + c];
        const float val = w + t0 * Bm[i] + t1 * Bm[64 + i] + t2 * Bm[128 + i] + t3 * Bm[192 + i];
        Wb[(size_t)(base + i) * 768 + c] = (_Float16)(val * scale);
    }
}

// ---------------------------------------------------------------------------
// BMx128 NT GEMM (BM = MF*32), BK=64, 4 waves (2x2), fp16 in / fp32 acc.
// Pipeline per K-step: ds_read ALL frags -> regs; barrier (LDS free); issue
// async stage of tile t+1 (global_load_lds); MFMAs from regs overlap the DMA;
// barrier (drains vmcnt) -> next iter reads the fresh tile. Single LDS buffer.
// 1-D grid with XCD-chunked swizzle: each XCD owns XB consecutive M-panels
// (A set ~1.6MB -> L2-resident) and sweeps N slowly.
// EPI 0 (MF=4): scatter into Q[96][1024][64], K4[96][kv/32][4][64][8],
//               V4[96][kv/16][64][16].
// EPI 1 (MF=2): +bias, fp32 out [M][768].
template <int EPI, int MF, int GX, int GY>
__global__ __launch_bounds__(256) void gemm_nt(const _Float16* __restrict__ A,
                                               const _Float16* __restrict__ B,
                                               int Kdim, void* __restrict__ Cout,
                                               const float* __restrict__ bias) {
    constexpr int BM = MF * 32;
    constexpr int XB = GX / 8;   // M-panels per XCD chunk
    __shared__ __align__(16) _Float16 As[BM * 64];
    __shared__ __align__(16) _Float16 Bs[128 * 64];
    const int tid = threadIdx.x;
    const int lane = tid & 63, wid = tid >> 6;
    const int l15 = lane & 15, l16 = lane >> 4;
    // XCD-chunked swizzle (bijective: GX*GY % 8 == 0, XB integral)
    const int id = blockIdx.x;
    const int xcd = id & 7, c = id >> 3;          // c in [0, GX*GY/8)
    const int bx = xcd * XB + (c % XB), by = c / XB;
    const int m0 = bx * BM, n0 = by << 7;
    const int wm = (wid >> 1) * (MF * 16), wn = (wid & 1) << 6;

    auto stage = [&](int k0) {
#pragma unroll
        for (int rr = 0; rr < MF; ++rr) {
            const int slot = (rr << 8) + tid;
            const int row = slot >> 3, sl = slot & 7;
            glds16(A + (size_t)(m0 + row) * Kdim + k0 + ((sl ^ (row & 7)) << 3),
                   (char*)As + (((rr << 8) + (wid << 6)) << 4));
        }
#pragma unroll
        for (int rr = 0; rr < 4; ++rr) {
            const int slot = (rr << 8) + tid;
            const int row = slot >> 3, sl = slot & 7;
            glds16(B + (size_t)(n0 + row) * Kdim + k0 + ((sl ^ (row & 7)) << 3),
                   (char*)Bs + (((rr << 8) + (wid << 6)) << 4));
        }
    };

    f32x4 acc[MF][4];
#pragma unroll
    for (int i = 0; i < MF; ++i)
#pragma unroll
        for (int j = 0; j < 4; ++j) acc[i][j] = (f32x4){0.f, 0.f, 0.f, 0.f};

    stage(0);
    __syncthreads();   // tile 0 landed (vmcnt drained by barrier semantics)

    for (int k0 = 0; k0 < Kdim; k0 += 64) {
        // read ALL fragments of this tile into registers
        f16x8 af[2][MF], bf[2][4];
#pragma unroll
        for (int kh = 0; kh < 2; ++kh) {
#pragma unroll
            for (int i = 0; i < MF; ++i) {
                const int ra = wm + i * 16 + l15;
                af[kh][i] = *(const f16x8*)((const char*)As + ra * 128 +
                                            ((((kh << 2) + l16) ^ (ra & 7)) << 4));
            }
#pragma unroll
            for (int j = 0; j < 4; ++j) {
                const int rb = wn + j * 16 + l15;
                bf[kh][j] = *(const f16x8*)((const char*)Bs + rb * 128 +
                                            ((((kh << 2) + l16) ^ (rb & 7)) << 4));
            }
        }
        __syncthreads();   // all LDS reads done -> buffer free for overwrite
        if (k0 + 64 < Kdim) stage(k0 + 64);   // async DMA of next tile
        __builtin_amdgcn_sched_barrier(0);    // keep MFMAs after stage issue
#pragma unroll
        for (int kh = 0; kh < 2; ++kh)
#pragma unroll
            for (int i = 0; i < MF; ++i)
#pragma unroll
                for (int j = 0; j < 4; ++j)
                    acc[i][j] = __builtin_amdgcn_mfma_f32_16x16x32_f16(af[kh][i], bf[kh][j],
                                                                       acc[i][j], 0, 0, 0);
        __syncthreads();   // staged tile landed (vmcnt drained)
    }

    if (EPI == 0) {
        _Float16* qkv = (_Float16*)Cout;
#pragma unroll
        for (int j = 0; j < 4; ++j) {
            const int col = n0 + wn + j * 16 + l15;   // 0..2303 = [3][12][64]
            const int which = col / 768;
            const int rem = col - which * 768;
            const int hh = rem >> 6, d = rem & 63;
#pragma unroll
            for (int i = 0; i < MF; ++i) {
                const int rowb = m0 + wm + i * 16 + (l16 << 2);  // b*1024+n, 4-aligned
                const int b = rowb >> 10, n = rowb & 1023;
                const int b12h = b * 12 + hh;
                if (which == 2) {
                    // V4[bh][n>>4][d][n&15]: 4 consecutive kv -> 8B store
                    f16x4 pk = { (_Float16)acc[i][j][0], (_Float16)acc[i][j][1],
                                 (_Float16)acc[i][j][2], (_Float16)acc[i][j][3] };
                    *(f16x4*)(qkv + 12582912 +
                              ((((size_t)b12h * 64 + (n >> 4)) * 64 + d) << 4) + (n & 15)) = pk;
                } else if (which == 1) {
                    // K4[bh][kv>>5][d>>4][(kv&31)*2 + ((d>>3)&1)][d&7]
                    const size_t hb = 6291456 + ((size_t)b12h << 16);
#pragma unroll
                    for (int r = 0; r < 4; ++r) {
                        const int kv = n + r;
                        const int off = ((((kv >> 5) << 2) + (d >> 4)) << 9) +
                                        ((((kv & 31) << 1) + ((d >> 3) & 1)) << 3) + (d & 7);
                        qkv[hb + off] = (_Float16)acc[i][j][r];
                    }
                } else {
#pragma unroll
                    for (int r = 0; r < 4; ++r)
                        qkv[(((size_t)b12h << 10) + n + r) * 64 + d] = (_Float16)acc[i][j][r];
                }
            }
        }
    } else {
        float* out = (float*)Cout;
#pragma unroll
        for (int j = 0; j < 4; ++j) {
            const int col = n0 + wn + j * 16 + l15;
            const float bv = bias[col];
#pragma unroll
            for (int i = 0; i < MF; ++i)
#pragma unroll
                for (int r = 0; r < 4; ++r) {
                    const int row = m0 + wm + i * 16 + (l16 << 2) + r;
                    out[(size_t)row * 768 + col] = acc[i][j][r] + bv;
                }
        }
    }
}

// ---------------------------------------------------------------------------
// Flash attention, swapped-operand structure, 32x32x16 MFMA, in-block split-KV,
// cross-segment S pipeline. 8 waves: waves 0-3 sweep kv[0:512), 4-7 sweep
// kv[512:1024), same 128 q rows. Segment(t):
//   [V(t) loads | QK^T(t+1)->stN (kf loaded last seg) | K(t+2) loads ->kf |
//    softmax(stC from last seg) | fragbuild (4-shfl) | PV(t)]
// vmcnt queue alternates strictly: QK^T waits only the K loads (vmcnt 4),
// PV waits only the V loads (vmcnt 4); every load has ~1 segment of cover,
// and QK^T's MFMA latency is hidden across the segment boundary.
__global__ __launch_bounds__(512, 4) void attn_kernel(const _Float16* __restrict__ Qg,
                                                      const _Float16* __restrict__ K4g,
                                                      const _Float16* __restrict__ V4g,
                                                      _Float16* __restrict__ AO) {
    __shared__ float lds_o[4][64][32];      // [wq][lane][32 partial O values]
    __shared__ float2 lds_ml[4][32];        // [wq][q-lane] (m, l)

    const int tid = threadIdx.x, lane = tid & 63, wid = tid >> 6;
    const int l31 = lane & 31, hi = lane >> 5;
    const int wq = wid & 3, kvhalf = wid >> 2;
    const int bh = blockIdx.x;             // b*12+h
    const int q = (blockIdx.y << 7) + (wq << 5) + l31;   // this lane's q row
    const int tbase = kvhalf << 4;         // first 32-kv tile (0 or 16)
    const _Float16* K4h = K4g + ((size_t)bh << 16);  // [32 t][4 kd][64 e][8]
    const _Float16* V4h = V4g + ((size_t)bh << 16);  // [64 vt][64 d][16 kv]

    // Q fragments (B-operand): lane holds Q[q][kd*16 + hi*8 + j]
    f16x8 qf[4];
#pragma unroll
    for (int kd = 0; kd < 4; ++kd)
        qf[kd] = *(const f16x8*)(Qg + (((size_t)bh << 10) + q) * 64 + kd * 16 + hi * 8);

    f32x16 o0, o1;   // O^T acc, d-tiles [0..31],[32..63]: all values belong to q
#pragma unroll
    for (int j = 0; j < 16; ++j) { o0[j] = 0.f; o1[j] = 0.f; }
    float m_run = -INFINITY, l_run = 0.f;

    f16x8 kf[4], vf[4];
    f32x16 stA, stB;

    // ---- prologue: QK^T of tile 0 into stA; kf <- K(tile 1)
#pragma unroll
    for (int kd = 0; kd < 4; ++kd)
        kf[kd] = *(const f16x8*)(K4h + ((size_t)((tbase << 2) + kd) << 9) +
                                 (((l31 << 1) + hi) << 3));
#pragma unroll
    for (int j = 0; j < 16; ++j) stA[j] = 0.f;
#pragma unroll
    for (int kd = 0; kd < 4; ++kd)
        stA = __builtin_amdgcn_mfma_f32_32x32x16_f16(kf[kd], qf[kd], stA, 0, 0, 0);
#pragma unroll
    for (int kd = 0; kd < 4; ++kd)
        kf[kd] = *(const f16x8*)(K4h + ((size_t)(((tbase + 1) << 2) + kd) << 9) +
                                 (((l31 << 1) + hi) << 3));

    auto seg = [&](int tl, f32x16& stC, f32x16& stN) {
        const int tt = tbase + tl;
        // V(t) loads, first in the vmcnt queue for this segment
#pragma unroll
        for (int dh = 0; dh < 2; ++dh)
#pragma unroll
            for (int ks = 0; ks < 2; ++ks)
                vf[dh * 2 + ks] = *(const f16x8*)(V4h + ((size_t)((tt << 1) + ks) << 10) +
                                                  ((dh * 32 + l31) << 4) + hi * 8);

        // QK^T(t+1) -> stN (kf holds K(t+1), loaded one segment ago)
#pragma unroll
        for (int j = 0; j < 16; ++j) stN[j] = 0.f;
#pragma unroll
        for (int kd = 0; kd < 4; ++kd)
            stN = __builtin_amdgcn_mfma_f32_32x32x16_f16(kf[kd], qf[kd], stN, 0, 0, 0);

        // kf <- K(t+2) (WAR; consumed next segment). Wraps harmlessly.
        const int tn = tbase + ((tl + 2) & 15);
#pragma unroll
        for (int kd = 0; kd < 4; ++kd)
            kf[kd] = *(const f16x8*)(K4h + ((size_t)((tn << 2) + kd) << 9) +
                                     (((l31 << 1) + hi) << 3));
        __builtin_amdgcn_sched_barrier(0);   // all loads issued before the VALU tail

        // ---- softmax on stC (tile t; computed one segment ago -> latency hidden)
        float tr[8];
#pragma unroll
        for (int j = 0; j < 8; ++j) tr[j] = fmaxf(stC[2 * j], stC[2 * j + 1]);
#pragma unroll
        for (int j = 0; j < 4; ++j) tr[j] = fmaxf(tr[j], tr[j + 4]);
        float mx = fmaxf(fmaxf(tr[0], tr[2]), fmaxf(tr[1], tr[3]));
        mx = fmaxf(mx, __shfl_xor(mx, 32));
        // defer-max (T13): only rescale when the max grew by > 8 (exp2 domain)
        if (!__all(mx <= m_run + 8.f)) {
            const float mnew = fmaxf(m_run, mx);
            const float fac = __builtin_amdgcn_exp2f(m_run - mnew);
            l_run *= fac;
#pragma unroll
            for (int j = 0; j < 16; ++j) { o0[j] *= fac; o1[j] *= fac; }
            m_run = mnew;
        }
        float p[16];
#pragma unroll
        for (int j = 0; j < 16; ++j) p[j] = __builtin_amdgcn_exp2f(stC[j] - m_run);
        float sr[8];
#pragma unroll
        for (int j = 0; j < 8; ++j) sr[j] = p[2 * j] + p[2 * j + 1];
#pragma unroll
        for (int j = 0; j < 4; ++j) sr[j] = sr[j] + sr[j + 4];
        float sum = (sr[0] + sr[2]) + (sr[1] + sr[3]);
        sum += __shfl_xor(sum, 32);
        l_run += sum;

        // ---- build PV B-fragments (4-shfl): p[r] holds kv=(r&3)+8*(r>>2)+4*hi.
        // hi=0 needs partner's a0,a1/a4,a5; hi=1 needs partner's a2,a3/a6,a7:
        // pre-select the word to send, one shfl serves both directions.
        const unsigned a0 = pkh(p[0], p[1]),   a1 = pkh(p[2], p[3]);
        const unsigned a2 = pkh(p[4], p[5]),   a3 = pkh(p[6], p[7]);
        const unsigned a4 = pkh(p[8], p[9]),   a5 = pkh(p[10], p[11]);
        const unsigned a6 = pkh(p[12], p[13]), a7 = pkh(p[14], p[15]);
        const unsigned s0 = (unsigned)__shfl_xor((int)(hi ? a0 : a2), 32);
        const unsigned s1 = (unsigned)__shfl_xor((int)(hi ? a1 : a3), 32);
        const unsigned s2 = (unsigned)__shfl_xor((int)(hi ? a4 : a6), 32);
        const unsigned s3 = (unsigned)__shfl_xor((int)(hi ? a5 : a7), 32);
        const u32x4 w0 = { hi ? s0 : a0, hi ? s1 : a1, hi ? a2 : s0, hi ? a3 : s1 };
        const u32x4 w1 = { hi ? s2 : a4, hi ? s3 : a5, hi ? a6 : s2, hi ? a7 : s3 };
        const f16x8 pa0 = __builtin_bit_cast(f16x8, w0);  // kv 0..15 slice
        const f16x8 pa1 = __builtin_bit_cast(f16x8, w1);  // kv 16..31 slice

        // O^T[d][q] += sum_kv V[kv][d] * P[q][kv]  (waits vf via vmcnt(4))
        o0 = __builtin_amdgcn_mfma_f32_32x32x16_f16(vf[0], pa0, o0, 0, 0, 0);
        o0 = __builtin_amdgcn_mfma_f32_32x32x16_f16(vf[1], pa1, o0, 0, 0, 0);
        o1 = __builtin_amdgcn_mfma_f32_32x32x16_f16(vf[2], pa0, o1, 0, 0, 0);
        o1 = __builtin_amdgcn_mfma_f32_32x32x16_f16(vf[3], pa1, o1, 0, 0, 0);
    };

#pragma unroll 1
    for (int k2 = 0; k2 < 8; ++k2) {
        seg(2 * k2,     stA, stB);
        seg(2 * k2 + 1, stB, stA);
    }

    // ---- in-block split-KV merge ----
    if (kvhalf) {
#pragma unroll
        for (int g = 0; g < 4; ++g) {
            *(f32x4*)&lds_o[wq][lane][4 * g] =
                (f32x4){o0[4 * g + 0], o0[4 * g + 1], o0[4 * g + 2], o0[4 * g + 3]};
            *(f32x4*)&lds_o[wq][lane][16 + 4 * g] =
                (f32x4){o1[4 * g + 0], o1[4 * g + 1], o1[4 * g + 2], o1[4 * g + 3]};
        }
        if (!hi) lds_ml[wq][l31] = make_float2(m_run, l_run);
    }
    __syncthreads();
    if (kvhalf) return;

    // waves 0-3: merge own partial with partner's (same q, same lane mapping)
    const float2 ml2 = lds_ml[wq][l31];
    const float M = fmaxf(m_run, ml2.x);
    const float f1 = __builtin_amdgcn_exp2f(m_run - M);
    const float f2 = __builtin_amdgcn_exp2f(ml2.x - M);
    const float inv = __builtin_amdgcn_rcpf(l_run * f1 + ml2.y * f2);
    const float c1 = f1 * inv, c2 = f2 * inv;

    // epilogue: AO[b][n=q][h*64+d];  d = t*32 + g*8 + hi*4 + i
    const int b = bh / 12, h = bh - (bh / 12) * 12;
    _Float16* dst = AO + ((size_t)b * 1024 + q) * 768 + h * 64 + hi * 4;
#pragma unroll
    for (int g = 0; g < 4; ++g) {
        const f32x4 p0 = *(const f32x4*)&lds_o[wq][lane][4 * g];
        const f32x4 p1 = *(const f32x4*)&lds_o[wq][lane][16 + 4 * g];
        const u32x2 w0 = { pkh(o0[4 * g + 0] * c1 + p0[0] * c2, o0[4 * g + 1] * c1 + p0[1] * c2),
                           pkh(o0[4 * g + 2] * c1 + p0[2] * c2, o0[4 * g + 3] * c1 + p0[3] * c2) };
        *(f16x4*)(dst + g * 8) = __builtin_bit_cast(f16x4, w0);
        const u32x2 w1 = { pkh(o1[4 * g + 0] * c1 + p1[0] * c2, o1[4 * g + 1] * c1 + p1[1] * c2),
                           pkh(o1[4 * g + 2] * c1 + p1[2] * c2, o1[4 * g + 3] * c1 + p1[3] * c2) };
        *(f16x4*)(dst + 32 + g * 8) = __builtin_bit_cast(f16x4, w1);
    }
}

// ---------------------------------------------------------------------------
extern "C" void kernel_launch(void* const* d_in, const int* in_sizes, int n_in,
                              void* d_out, int out_size, void* d_ws, size_t ws_size,
                              hipStream_t stream) {
    (void)in_sizes; (void)n_in; (void)out_size; (void)ws_size;
    const float* x     = (const float*)d_in[0];
    const float* Wqkv  = (const float*)d_in[1];
    const float* Wproj = (const float*)d_in[2];
    const float* bproj = (const float*)d_in[3];
    const float* Aq    = (const float*)d_in[4];
    const float* Bq    = (const float*)d_in[5];
    const float* Av    = (const float*)d_in[6];
    const float* Bv    = (const float*)d_in[7];

    // workspace layout (fp16 elements)
    _Float16* Xb     = (_Float16*)d_ws;          // [8192][768]
    _Float16* Wqkvb  = Xb + 6291456;             // [2304][768]
    _Float16* Wprojb = Wqkvb + 1769472;          // [768][768]
    _Float16* QKV    = Wprojb + 589824;          // Q[96][1024][64] K4[96][...] V4[96][...]
    _Float16* AO     = QKV + 18874368;           // [8192][768]
    float* out = (float*)d_out;

    cast_f32_f16<<<6144, 256, 0, stream>>>(x, Xb, 1572864);
    cast_f32_f16<<<576, 256, 0, stream>>>(Wqkv + 589824, Wqkvb + 589824, 147456);  // K rows
    cast_f32_f16<<<576, 256, 0, stream>>>(Wproj, Wprojb, 147456);
    prep_w<<<dim3(24, 3), 256, 0, stream>>>(Wqkv, Aq, Bq, Av, Bv, Wqkvb);

    // gemm0: grid 64x18 = 1152 blocks (1-D, XCD-swizzled in-kernel)
    gemm_nt<0, 4, 64, 18><<<1152, 256, 0, stream>>>(Xb, Wqkvb, 768, (void*)QKV, nullptr);
    attn_kernel<<<dim3(96, 8), 512, 0, stream>>>(QKV, QKV + 6291456, QKV + 12582912, AO);
    // gemm1: grid 128x6 = 768 blocks (1-D, XCD-swizzled in-kernel)
    gemm_nt<1, 2, 128, 6><<<768, 256, 0, stream>>>(AO, Wprojb, 768, (void*)out, bproj);
}

// Round 10
// 126.095 us; speedup vs baseline: 1.0696x; 1.0696x over previous
//
#include <hip/hip_runtime.h>

#define DEV __device__ __forceinline__

typedef _Float16 f16x8 __attribute__((ext_vector_type(8)));
typedef _Float16 f16x4 __attribute__((ext_vector_type(4)));
typedef float f32x4 __attribute__((ext_vector_type(4)));
typedef float f32x16 __attribute__((ext_vector_type(16)));
typedef unsigned int u32x4 __attribute__((ext_vector_type(4)));
typedef unsigned int u32x2 __attribute__((ext_vector_type(2)));

// async global->LDS, 16B per lane. LDS dest must be wave-uniform base (+lane*16 in HW).
DEV void glds16(const void* g, void* l) {
    __builtin_amdgcn_global_load_lds(
        (const __attribute__((address_space(1))) void*)g,
        (__attribute__((address_space(3))) void*)l, 16, 0, 0);
}

DEV unsigned pkh(float lo, float hi) {
    return __builtin_bit_cast(unsigned, __builtin_amdgcn_cvt_pkrtz(lo, hi));
}

// ---------------------------------------------------------------------------
// cast fp32 -> fp16, 4 elems/thread
__global__ __launch_bounds__(256) void cast_f32_f16(const float* __restrict__ src,
                                                    _Float16* __restrict__ dst, int n4) {
    const int i = blockIdx.x * 256 + threadIdx.x;
    if (i >= n4) return;
    const float4 v = ((const float4*)src)[i];
    f16x4 o = { (_Float16)v.x, (_Float16)v.y, (_Float16)v.z, (_Float16)v.w };
    *(f16x4*)(dst + (size_t)i * 4) = o;
}

// ---------------------------------------------------------------------------
// Fold LoRA (I + A B) into Q/V sections of Wqkv; fold softmax scale AND log2(e)
// into Q (attention uses exp2-domain softmax). grid (24, 3): no c-loop.
__global__ __launch_bounds__(256) void prep_w(const float* __restrict__ W,
                                              const float* __restrict__ Aq,
                                              const float* __restrict__ Bq,
                                              const float* __restrict__ Av,
                                              const float* __restrict__ Bv,
                                              _Float16* __restrict__ Wb) {
    const int bx = blockIdx.x;         // 0..23: 12 Q heads then 12 V heads
    const int sec = bx / 12;           // 0 = Q, 1 = V
    const int h = bx - sec * 12;
    const float* Am = sec ? Av : Aq;   // [64][4]
    const float* Bm = sec ? Bv : Bq;   // [4][64]
    const int base = sec ? (1536 + h * 64) : (h * 64);
    const float scale = sec ? 1.0f : (0.125f * 1.4426950408889634f);
    const int c = blockIdx.y * 256 + threadIdx.x;
    float t0 = 0.f, t1 = 0.f, t2 = 0.f, t3 = 0.f;
    for (int j = 0; j < 64; ++j) {
        const float w = W[(size_t)(base + j) * 768 + c];
        t0 += Am[j * 4 + 0] * w;
        t1 += Am[j * 4 + 1] * w;
        t2 += Am[j * 4 + 2] * w;
        t3 += Am[j * 4 + 3] * w;
    }
    for (int i = 0; i < 64; ++i) {
        const float w = W[(size_t)(base + i) * 768 + c];
        const float val = w + t0 * Bm[i] + t1 * Bm[64 + i] + t2 * Bm[128 + i] + t3 * Bm[192 + i];
        Wb[(size_t)(base + i) * 768 + c] = (_Float16)(val * scale);
    }
}

// ---------------------------------------------------------------------------
// BMx128 NT GEMM (BM = MF*32), BK=64, 4 waves (2x2), fp16 in / fp32 acc.
// Pipeline per K-step: ds_read ALL frags -> regs; barrier (LDS free); issue
// async stage of tile t+1 (global_load_lds); MFMAs from regs overlap the DMA;
// barrier (drains vmcnt) -> next iter reads the fresh tile. Single LDS buffer.
// 1-D grid with XCD-chunked swizzle.
// EPI 0 (MF=4): scatter into Q[96][1024][64], K4[96][kv/32][4][64][8],
//               V4[96][kv/16][64][16].
// EPI 1 (MF=2): +bias, fp32 out [M][768].
template <int EPI, int MF, int GX, int GY>
__global__ __launch_bounds__(256) void gemm_nt(const _Float16* __restrict__ A,
                                               const _Float16* __restrict__ B,
                                               int Kdim, void* __restrict__ Cout,
                                               const float* __restrict__ bias) {
    constexpr int BM = MF * 32;
    constexpr int XB = GX / 8;   // M-panels per XCD chunk
    __shared__ __align__(16) _Float16 As[BM * 64];
    __shared__ __align__(16) _Float16 Bs[128 * 64];
    const int tid = threadIdx.x;
    const int lane = tid & 63, wid = tid >> 6;
    const int l15 = lane & 15, l16 = lane >> 4;
    // XCD-chunked swizzle (bijective: GX*GY % 8 == 0, XB integral)
    const int id = blockIdx.x;
    const int xcd = id & 7, c = id >> 3;          // c in [0, GX*GY/8)
    const int bx = xcd * XB + (c % XB), by = c / XB;
    const int m0 = bx * BM, n0 = by << 7;
    const int wm = (wid >> 1) * (MF * 16), wn = (wid & 1) << 6;

    auto stage = [&](int k0) {
#pragma unroll
        for (int rr = 0; rr < MF; ++rr) {
            const int slot = (rr << 8) + tid;
            const int row = slot >> 3, sl = slot & 7;
            glds16(A + (size_t)(m0 + row) * Kdim + k0 + ((sl ^ (row & 7)) << 3),
                   (char*)As + (((rr << 8) + (wid << 6)) << 4));
        }
#pragma unroll
        for (int rr = 0; rr < 4; ++rr) {
            const int slot = (rr << 8) + tid;
            const int row = slot >> 3, sl = slot & 7;
            glds16(B + (size_t)(n0 + row) * Kdim + k0 + ((sl ^ (row & 7)) << 3),
                   (char*)Bs + (((rr << 8) + (wid << 6)) << 4));
        }
    };

    f32x4 acc[MF][4];
#pragma unroll
    for (int i = 0; i < MF; ++i)
#pragma unroll
        for (int j = 0; j < 4; ++j) acc[i][j] = (f32x4){0.f, 0.f, 0.f, 0.f};

    stage(0);
    __syncthreads();   // tile 0 landed (vmcnt drained by barrier semantics)

    for (int k0 = 0; k0 < Kdim; k0 += 64) {
        // read ALL fragments of this tile into registers
        f16x8 af[2][MF], bf[2][4];
#pragma unroll
        for (int kh = 0; kh < 2; ++kh) {
#pragma unroll
            for (int i = 0; i < MF; ++i) {
                const int ra = wm + i * 16 + l15;
                af[kh][i] = *(const f16x8*)((const char*)As + ra * 128 +
                                            ((((kh << 2) + l16) ^ (ra & 7)) << 4));
            }
#pragma unroll
            for (int j = 0; j < 4; ++j) {
                const int rb = wn + j * 16 + l15;
                bf[kh][j] = *(const f16x8*)((const char*)Bs + rb * 128 +
                                            ((((kh << 2) + l16) ^ (rb & 7)) << 4));
            }
        }
        __syncthreads();   // all LDS reads done -> buffer free for overwrite
        if (k0 + 64 < Kdim) stage(k0 + 64);   // async DMA of next tile
        __builtin_amdgcn_sched_barrier(0);    // keep MFMAs after stage issue
#pragma unroll
        for (int kh = 0; kh < 2; ++kh)
#pragma unroll
            for (int i = 0; i < MF; ++i)
#pragma unroll
                for (int j = 0; j < 4; ++j)
                    acc[i][j] = __builtin_amdgcn_mfma_f32_16x16x32_f16(af[kh][i], bf[kh][j],
                                                                       acc[i][j], 0, 0, 0);
        __syncthreads();   // staged tile landed (vmcnt drained)
    }

    if (EPI == 0) {
        _Float16* qkv = (_Float16*)Cout;
#pragma unroll
        for (int j = 0; j < 4; ++j) {
            const int col = n0 + wn + j * 16 + l15;   // 0..2303 = [3][12][64]
            const int which = col / 768;
            const int rem = col - which * 768;
            const int hh = rem >> 6, d = rem & 63;
#pragma unroll
            for (int i = 0; i < MF; ++i) {
                const int rowb = m0 + wm + i * 16 + (l16 << 2);  // b*1024+n, 4-aligned
                const int b = rowb >> 10, n = rowb & 1023;
                const int b12h = b * 12 + hh;
                if (which == 2) {
                    // V4[bh][n>>4][d][n&15]: 4 consecutive kv -> 8B store
                    f16x4 pk = { (_Float16)acc[i][j][0], (_Float16)acc[i][j][1],
                                 (_Float16)acc[i][j][2], (_Float16)acc[i][j][3] };
                    *(f16x4*)(qkv + 12582912 +
                              ((((size_t)b12h * 64 + (n >> 4)) * 64 + d) << 4) + (n & 15)) = pk;
                } else if (which == 1) {
                    // K4[bh][kv>>5][d>>4][(kv&31)*2 + ((d>>3)&1)][d&7]
                    const size_t hb = 6291456 + ((size_t)b12h << 16);
#pragma unroll
                    for (int r = 0; r < 4; ++r) {
                        const int kv = n + r;
                        const int off = ((((kv >> 5) << 2) + (d >> 4)) << 9) +
                                        ((((kv & 31) << 1) + ((d >> 3) & 1)) << 3) + (d & 7);
                        qkv[hb + off] = (_Float16)acc[i][j][r];
                    }
                } else {
#pragma unroll
                    for (int r = 0; r < 4; ++r)
                        qkv[(((size_t)b12h << 10) + n + r) * 64 + d] = (_Float16)acc[i][j][r];
                }
            }
        }
    } else {
        float* out = (float*)Cout;
#pragma unroll
        for (int j = 0; j < 4; ++j) {
            const int col = n0 + wn + j * 16 + l15;
            const float bv = bias[col];
#pragma unroll
            for (int i = 0; i < MF; ++i)
#pragma unroll
                for (int r = 0; r < 4; ++r) {
                    const int row = m0 + wm + i * 16 + (l16 << 2) + r;
                    out[(size_t)row * 768 + col] = acc[i][j][r] + bv;
                }
        }
    }
}

// ---------------------------------------------------------------------------
// Flash attention, swapped-operand structure, 32x32x16 MFMA, in-block split-KV,
// single-st cross-segment pipeline (<=128 VGPR by construction).
// Segment(t): [V(t) loads | softmax(st = S(t), computed last seg) -> p |
//              QK^T(t+1) -> st (REUSES st: WAR, p already extracted) |
//              K(t+2) loads -> kf | 4-shfl fragbuild | PV(t)]
// QK^T's MFMA latency is covered by fragbuild+PV+next V loads; every global
// load has >= 1 segment of cover; vmcnt queue alternates V/K strictly so PV
// waits only V and QK^T waits only K.
__global__ __launch_bounds__(512) void attn_kernel(const _Float16* __restrict__ Qg,
                                                   const _Float16* __restrict__ K4g,
                                                   const _Float16* __restrict__ V4g,
                                                   _Float16* __restrict__ AO) {
    __shared__ float lds_o[4][64][32];      // [wq][lane][32 partial O values]
    __shared__ float2 lds_ml[4][32];        // [wq][q-lane] (m, l)

    const int tid = threadIdx.x, lane = tid & 63, wid = tid >> 6;
    const int l31 = lane & 31, hi = lane >> 5;
    const int wq = wid & 3, kvhalf = wid >> 2;
    const int bh = blockIdx.x;             // b*12+h
    const int q = (blockIdx.y << 7) + (wq << 5) + l31;   // this lane's q row
    const int tbase = kvhalf << 4;         // first 32-kv tile (0 or 16)
    const _Float16* K4h = K4g + ((size_t)bh << 16);  // [32 t][4 kd][64 e][8]
    const _Float16* V4h = V4g + ((size_t)bh << 16);  // [64 vt][64 d][16 kv]

    // Q fragments (B-operand): lane holds Q[q][kd*16 + hi*8 + j]
    f16x8 qf[4];
#pragma unroll
    for (int kd = 0; kd < 4; ++kd)
        qf[kd] = *(const f16x8*)(Qg + (((size_t)bh << 10) + q) * 64 + kd * 16 + hi * 8);

    f32x16 o0, o1;   // O^T acc, d-tiles [0..31],[32..63]: all values belong to q
#pragma unroll
    for (int j = 0; j < 16; ++j) { o0[j] = 0.f; o1[j] = 0.f; }
    float m_run = -INFINITY, l_run = 0.f;

    f16x8 kf[4], vf[4];
    f32x16 st;

    // ---- prologue: QK^T of tile tbase into st; kf <- K(tbase+1)
#pragma unroll
    for (int kd = 0; kd < 4; ++kd)
        kf[kd] = *(const f16x8*)(K4h + ((size_t)((tbase << 2) + kd) << 9) +
                                 (((l31 << 1) + hi) << 3));
#pragma unroll
    for (int j = 0; j < 16; ++j) st[j] = 0.f;
#pragma unroll
    for (int kd = 0; kd < 4; ++kd)
        st = __builtin_amdgcn_mfma_f32_32x32x16_f16(kf[kd], qf[kd], st, 0, 0, 0);
#pragma unroll
    for (int kd = 0; kd < 4; ++kd)
        kf[kd] = *(const f16x8*)(K4h + ((size_t)(((tbase + 1) << 2) + kd) << 9) +
                                 (((l31 << 1) + hi) << 3));

#pragma unroll 1
    for (int kt = 0; kt < 16; ++kt) {
        const int tt = tbase + kt;

        // V(t) loads, first in the vmcnt queue for this segment
#pragma unroll
        for (int dh = 0; dh < 2; ++dh)
#pragma unroll
            for (int ks = 0; ks < 2; ++ks)
                vf[dh * 2 + ks] = *(const f16x8*)(V4h + ((size_t)((tt << 1) + ks) << 10) +
                                                  ((dh * 32 + l31) << 4) + hi * 8);

        // ---- softmax on st = S(tile t), computed one segment ago (latency hidden)
        float tr[8];
#pragma unroll
        for (int j = 0; j < 8; ++j) tr[j] = fmaxf(st[2 * j], st[2 * j + 1]);
#pragma unroll
        for (int j = 0; j < 4; ++j) tr[j] = fmaxf(tr[j], tr[j + 4]);
        float mx = fmaxf(fmaxf(tr[0], tr[2]), fmaxf(tr[1], tr[3]));
        mx = fmaxf(mx, __shfl_xor(mx, 32));
        // defer-max (T13): only rescale when the max grew by > 8 (exp2 domain)
        if (!__all(mx <= m_run + 8.f)) {
            const float mnew = fmaxf(m_run, mx);
            const float fac = __builtin_amdgcn_exp2f(m_run - mnew);
            l_run *= fac;
#pragma unroll
            for (int j = 0; j < 16; ++j) { o0[j] *= fac; o1[j] *= fac; }
            m_run = mnew;
        }
        float p[16];
#pragma unroll
        for (int j = 0; j < 16; ++j) p[j] = __builtin_amdgcn_exp2f(st[j] - m_run);
        float sr[8];
#pragma unroll
        for (int j = 0; j < 8; ++j) sr[j] = p[2 * j] + p[2 * j + 1];
#pragma unroll
        for (int j = 0; j < 4; ++j) sr[j] = sr[j] + sr[j + 4];
        float sum = (sr[0] + sr[2]) + (sr[1] + sr[3]);
        sum += __shfl_xor(sum, 32);
        l_run += sum;

        // ---- QK^T(t+1) -> st (reuse: p extracted, st dead). kf = K(t+1).
#pragma unroll
        for (int j = 0; j < 16; ++j) st[j] = 0.f;
#pragma unroll
        for (int kd = 0; kd < 4; ++kd)
            st = __builtin_amdgcn_mfma_f32_32x32x16_f16(kf[kd], qf[kd], st, 0, 0, 0);

        // kf <- K(t+2) (WAR after QK^T issue; consumed next segment). Wraps.
        const int tn = tbase + ((kt + 2) & 15);
#pragma unroll
        for (int kd = 0; kd < 4; ++kd)
            kf[kd] = *(const f16x8*)(K4h + ((size_t)((tn << 2) + kd) << 9) +
                                     (((l31 << 1) + hi) << 3));
        __builtin_amdgcn_sched_barrier(0);   // all loads issued before the VALU tail

        // ---- build PV B-fragments (4-shfl, HW-verified r9): p[r] holds
        // kv=(r&3)+8*(r>>2)+4*hi; pre-select the word to send, one shfl both ways.
        const unsigned a0 = pkh(p[0], p[1]),   a1 = pkh(p[2], p[3]);
        const unsigned a2 = pkh(p[4], p[5]),   a3 = pkh(p[6], p[7]);
        const unsigned a4 = pkh(p[8], p[9]),   a5 = pkh(p[10], p[11]);
        const unsigned a6 = pkh(p[12], p[13]), a7 = pkh(p[14], p[15]);
        const unsigned s0 = (unsigned)__shfl_xor((int)(hi ? a0 : a2), 32);
        const unsigned s1 = (unsigned)__shfl_xor((int)(hi ? a1 : a3), 32);
        const unsigned s2 = (unsigned)__shfl_xor((int)(hi ? a4 : a6), 32);
        const unsigned s3 = (unsigned)__shfl_xor((int)(hi ? a5 : a7), 32);
        const u32x4 w0 = { hi ? s0 : a0, hi ? s1 : a1, hi ? a2 : s0, hi ? a3 : s1 };
        const u32x4 w1 = { hi ? s2 : a4, hi ? s3 : a5, hi ? a6 : s2, hi ? a7 : s3 };
        const f16x8 pa0 = __builtin_bit_cast(f16x8, w0);  // kv 0..15 slice
        const f16x8 pa1 = __builtin_bit_cast(f16x8, w1);  // kv 16..31 slice

        // O^T[d][q] += sum_kv V[kv][d] * P[q][kv]  (waits vf via vmcnt(4))
        o0 = __builtin_amdgcn_mfma_f32_32x32x16_f16(vf[0], pa0, o0, 0, 0, 0);
        o0 = __builtin_amdgcn_mfma_f32_32x32x16_f16(vf[1], pa1, o0, 0, 0, 0);
        o1 = __builtin_amdgcn_mfma_f32_32x32x16_f16(vf[2], pa0, o1, 0, 0, 0);
        o1 = __builtin_amdgcn_mfma_f32_32x32x16_f16(vf[3], pa1, o1, 0, 0, 0);
    }

    // ---- in-block split-KV merge ----
    if (kvhalf) {
#pragma unroll
        for (int g = 0; g < 4; ++g) {
            *(f32x4*)&lds_o[wq][lane][4 * g] =
                (f32x4){o0[4 * g + 0], o0[4 * g + 1], o0[4 * g + 2], o0[4 * g + 3]};
            *(f32x4*)&lds_o[wq][lane][16 + 4 * g] =
                (f32x4){o1[4 * g + 0], o1[4 * g + 1], o1[4 * g + 2], o1[4 * g + 3]};
        }
        if (!hi) lds_ml[wq][l31] = make_float2(m_run, l_run);
    }
    __syncthreads();
    if (kvhalf) return;

    // waves 0-3: merge own partial with partner's (same q, same lane mapping)
    const float2 ml2 = lds_ml[wq][l31];
    const float M = fmaxf(m_run, ml2.x);
    const float f1 = __builtin_amdgcn_exp2f(m_run - M);
    const float f2 = __builtin_amdgcn_exp2f(ml2.x - M);
    const float inv = __builtin_amdgcn_rcpf(l_run * f1 + ml2.y * f2);
    const float c1 = f1 * inv, c2 = f2 * inv;

    // epilogue: AO[b][n=q][h*64+d];  d = t*32 + g*8 + hi*4 + i
    const int b = bh / 12, h = bh - (bh / 12) * 12;
    _Float16* dst = AO + ((size_t)b * 1024 + q) * 768 + h * 64 + hi * 4;
#pragma unroll
    for (int g = 0; g < 4; ++g) {
        const f32x4 p0 = *(const f32x4*)&lds_o[wq][lane][4 * g];
        const f32x4 p1 = *(const f32x4*)&lds_o[wq][lane][16 + 4 * g];
        const u32x2 w0 = { pkh(o0[4 * g + 0] * c1 + p0[0] * c2, o0[4 * g + 1] * c1 + p0[1] * c2),
                           pkh(o0[4 * g + 2] * c1 + p0[2] * c2, o0[4 * g + 3] * c1 + p0[3] * c2) };
        *(f16x4*)(dst + g * 8) = __builtin_bit_cast(f16x4, w0);
        const u32x2 w1 = { pkh(o1[4 * g + 0] * c1 + p1[0] * c2, o1[4 * g + 1] * c1 + p1[1] * c2),
                           pkh(o1[4 * g + 2] * c1 + p1[2] * c2, o1[4 * g + 3] * c1 + p1[3] * c2) };
        *(f16x4*)(dst + 32 + g * 8) = __builtin_bit_cast(f16x4, w1);
    }
}

// ---------------------------------------------------------------------------
extern "C" void kernel_launch(void* const* d_in, const int* in_sizes, int n_in,
                              void* d_out, int out_size, void* d_ws, size_t ws_size,
                              hipStream_t stream) {
    (void)in_sizes; (void)n_in; (void)out_size; (void)ws_size;
    const float* x     = (const float*)d_in[0];
    const float* Wqkv  = (const float*)d_in[1];
    const float* Wproj = (const float*)d_in[2];
    const float* bproj = (const float*)d_in[3];
    const float* Aq    = (const float*)d_in[4];
    const float* Bq    = (const float*)d_in[5];
    const float* Av    = (const float*)d_in[6];
    const float* Bv    = (const float*)d_in[7];

    // workspace layout (fp16 elements)
    _Float16* Xb     = (_Float16*)d_ws;          // [8192][768]
    _Float16* Wqkvb  = Xb + 6291456;             // [2304][768]
    _Float16* Wprojb = Wqkvb + 1769472;          // [768][768]
    _Float16* QKV    = Wprojb + 589824;          // Q[96][1024][64] K4[96][...] V4[96][...]
    _Float16* AO     = QKV + 18874368;           // [8192][768]
    float* out = (float*)d_out;

    cast_f32_f16<<<6144, 256, 0, stream>>>(x, Xb, 1572864);
    cast_f32_f16<<<576, 256, 0, stream>>>(Wqkv + 589824, Wqkvb + 589824, 147456);  // K rows
    cast_f32_f16<<<576, 256, 0, stream>>>(Wproj, Wprojb, 147456);
    prep_w<<<dim3(24, 3), 256, 0, stream>>>(Wqkv, Aq, Bq, Av, Bv, Wqkvb);

    // gemm0: grid 64x18 = 1152 blocks (1-D, XCD-swizzled in-kernel)
    gemm_nt<0, 4, 64, 18><<<1152, 256, 0, stream>>>(Xb, Wqkvb, 768, (void*)QKV, nullptr);
    attn_kernel<<<dim3(96, 8), 512, 0, stream>>>(QKV, QKV + 6291456, QKV + 12582912, AO);
    // gemm1: grid 128x6 = 768 blocks (1-D, XCD-swizzled in-kernel)
    gemm_nt<1, 2, 128, 6><<<768, 256, 0, stream>>>(AO, Wprojb, 768, (void*)out, bproj);
}

// Round 11
// 121.719 us; speedup vs baseline: 1.1080x; 1.0360x over previous
//
#include <hip/hip_runtime.h>

#define DEV __device__ __forceinline__

typedef _Float16 f16x8 __attribute__((ext_vector_type(8)));
typedef _Float16 f16x4 __attribute__((ext_vector_type(4)));
typedef float f32x4 __attribute__((ext_vector_type(4)));
typedef float f32x16 __attribute__((ext_vector_type(16)));
typedef unsigned int u32x4 __attribute__((ext_vector_type(4)));
typedef unsigned int u32x2 __attribute__((ext_vector_type(2)));

// async global->LDS, 16B per lane. LDS dest must be wave-uniform base (+lane*16 in HW).
DEV void glds16(const void* g, void* l) {
    __builtin_amdgcn_global_load_lds(
        (const __attribute__((address_space(1))) void*)g,
        (__attribute__((address_space(3))) void*)l, 16, 0, 0);
}

DEV unsigned pkh(float lo, float hi) {
    return __builtin_bit_cast(unsigned, __builtin_amdgcn_cvt_pkrtz(lo, hi));
}

// ---------------------------------------------------------------------------
// cast fp32 -> fp16, 4 elems/thread
__global__ __launch_bounds__(256) void cast_f32_f16(const float* __restrict__ src,
                                                    _Float16* __restrict__ dst, int n4) {
    const int i = blockIdx.x * 256 + threadIdx.x;
    if (i >= n4) return;
    const float4 v = ((const float4*)src)[i];
    f16x4 o = { (_Float16)v.x, (_Float16)v.y, (_Float16)v.z, (_Float16)v.w };
    *(f16x4*)(dst + (size_t)i * 4) = o;
}

// ---------------------------------------------------------------------------
// Fold LoRA (I + A B) into Q/V sections of Wqkv; fold softmax scale AND log2(e)
// into Q (attention uses exp2-domain softmax). grid (24, 3): no c-loop.
__global__ __launch_bounds__(256) void prep_w(const float* __restrict__ W,
                                              const float* __restrict__ Aq,
                                              const float* __restrict__ Bq,
                                              const float* __restrict__ Av,
                                              const float* __restrict__ Bv,
                                              _Float16* __restrict__ Wb) {
    const int bx = blockIdx.x;         // 0..23: 12 Q heads then 12 V heads
    const int sec = bx / 12;           // 0 = Q, 1 = V
    const int h = bx - sec * 12;
    const float* Am = sec ? Av : Aq;   // [64][4]
    const float* Bm = sec ? Bv : Bq;   // [4][64]
    const int base = sec ? (1536 + h * 64) : (h * 64);
    const float scale = sec ? 1.0f : (0.125f * 1.4426950408889634f);
    const int c = blockIdx.y * 256 + threadIdx.x;
    float t0 = 0.f, t1 = 0.f, t2 = 0.f, t3 = 0.f;
    for (int j = 0; j < 64; ++j) {
        const float w = W[(size_t)(base + j) * 768 + c];
        t0 += Am[j * 4 + 0] * w;
        t1 += Am[j * 4 + 1] * w;
        t2 += Am[j * 4 + 2] * w;
        t3 += Am[j * 4 + 3] * w;
    }
    for (int i = 0; i < 64; ++i) {
        const float w = W[(size_t)(base + i) * 768 + c];
        const float val = w + t0 * Bm[i] + t1 * Bm[64 + i] + t2 * Bm[128 + i] + t3 * Bm[192 + i];
        Wb[(size_t)(base + i) * 768 + c] = (_Float16)(val * scale);
    }
}

// ---------------------------------------------------------------------------
// BMx128 NT GEMM (BM = MF*32), BK=64, 4 waves (2x2), fp16 in / fp32 acc.
// Pipeline per K-step: ds_read ALL frags -> regs; barrier (LDS free); issue
// async stage of tile t+1 (global_load_lds); MFMAs from regs overlap the DMA;
// barrier (drains vmcnt) -> next iter reads the fresh tile. Single LDS buffer.
// 1-D grid with XCD-chunked swizzle.
// EPI 0 (MF=4): scatter into Q[96][1024][64], K4[96][kv/32][4][64][8],
//               V4[96][kv/16][64][16].
// EPI 1 (MF=2): +bias, fp32 out [M][768].
template <int EPI, int MF, int GX, int GY>
__global__ __launch_bounds__(256) void gemm_nt(const _Float16* __restrict__ A,
                                               const _Float16* __restrict__ B,
                                               int Kdim, void* __restrict__ Cout,
                                               const float* __restrict__ bias) {
    constexpr int BM = MF * 32;
    constexpr int XB = GX / 8;   // M-panels per XCD chunk
    __shared__ __align__(16) _Float16 As[BM * 64];
    __shared__ __align__(16) _Float16 Bs[128 * 64];
    const int tid = threadIdx.x;
    const int lane = tid & 63, wid = tid >> 6;
    const int l15 = lane & 15, l16 = lane >> 4;
    // XCD-chunked swizzle (bijective: GX*GY % 8 == 0, XB integral)
    const int id = blockIdx.x;
    const int xcd = id & 7, c = id >> 3;          // c in [0, GX*GY/8)
    const int bx = xcd * XB + (c % XB), by = c / XB;
    const int m0 = bx * BM, n0 = by << 7;
    const int wm = (wid >> 1) * (MF * 16), wn = (wid & 1) << 6;

    auto stage = [&](int k0) {
#pragma unroll
        for (int rr = 0; rr < MF; ++rr) {
            const int slot = (rr << 8) + tid;
            const int row = slot >> 3, sl = slot & 7;
            glds16(A + (size_t)(m0 + row) * Kdim + k0 + ((sl ^ (row & 7)) << 3),
                   (char*)As + (((rr << 8) + (wid << 6)) << 4));
        }
#pragma unroll
        for (int rr = 0; rr < 4; ++rr) {
            const int slot = (rr << 8) + tid;
            const int row = slot >> 3, sl = slot & 7;
            glds16(B + (size_t)(n0 + row) * Kdim + k0 + ((sl ^ (row & 7)) << 3),
                   (char*)Bs + (((rr << 8) + (wid << 6)) << 4));
        }
    };

    f32x4 acc[MF][4];
#pragma unroll
    for (int i = 0; i < MF; ++i)
#pragma unroll
        for (int j = 0; j < 4; ++j) acc[i][j] = (f32x4){0.f, 0.f, 0.f, 0.f};

    stage(0);
    __syncthreads();   // tile 0 landed (vmcnt drained by barrier semantics)

    for (int k0 = 0; k0 < Kdim; k0 += 64) {
        // read ALL fragments of this tile into registers
        f16x8 af[2][MF], bf[2][4];
#pragma unroll
        for (int kh = 0; kh < 2; ++kh) {
#pragma unroll
            for (int i = 0; i < MF; ++i) {
                const int ra = wm + i * 16 + l15;
                af[kh][i] = *(const f16x8*)((const char*)As + ra * 128 +
                                            ((((kh << 2) + l16) ^ (ra & 7)) << 4));
            }
#pragma unroll
            for (int j = 0; j < 4; ++j) {
                const int rb = wn + j * 16 + l15;
                bf[kh][j] = *(const f16x8*)((const char*)Bs + rb * 128 +
                                            ((((kh << 2) + l16) ^ (rb & 7)) << 4));
            }
        }
        __syncthreads();   // all LDS reads done -> buffer free for overwrite
        if (k0 + 64 < Kdim) stage(k0 + 64);   // async DMA of next tile
        __builtin_amdgcn_sched_barrier(0);    // keep MFMAs after stage issue
#pragma unroll
        for (int kh = 0; kh < 2; ++kh)
#pragma unroll
            for (int i = 0; i < MF; ++i)
#pragma unroll
                for (int j = 0; j < 4; ++j)
                    acc[i][j] = __builtin_amdgcn_mfma_f32_16x16x32_f16(af[kh][i], bf[kh][j],
                                                                       acc[i][j], 0, 0, 0);
        __syncthreads();   // staged tile landed (vmcnt drained)
    }

    if (EPI == 0) {
        _Float16* qkv = (_Float16*)Cout;
#pragma unroll
        for (int j = 0; j < 4; ++j) {
            const int col = n0 + wn + j * 16 + l15;   // 0..2303 = [3][12][64]
            const int which = col / 768;
            const int rem = col - which * 768;
            const int hh = rem >> 6, d = rem & 63;
#pragma unroll
            for (int i = 0; i < MF; ++i) {
                const int rowb = m0 + wm + i * 16 + (l16 << 2);  // b*1024+n, 4-aligned
                const int b = rowb >> 10, n = rowb & 1023;
                const int b12h = b * 12 + hh;
                if (which == 2) {
                    // V4[bh][n>>4][d][n&15]: 4 consecutive kv -> 8B store
                    f16x4 pk = { (_Float16)acc[i][j][0], (_Float16)acc[i][j][1],
                                 (_Float16)acc[i][j][2], (_Float16)acc[i][j][3] };
                    *(f16x4*)(qkv + 12582912 +
                              ((((size_t)b12h * 64 + (n >> 4)) * 64 + d) << 4) + (n & 15)) = pk;
                } else if (which == 1) {
                    // K4[bh][kv>>5][d>>4][(kv&31)*2 + ((d>>3)&1)][d&7]
                    const size_t hb = 6291456 + ((size_t)b12h << 16);
#pragma unroll
                    for (int r = 0; r < 4; ++r) {
                        const int kv = n + r;
                        const int off = ((((kv >> 5) << 2) + (d >> 4)) << 9) +
                                        ((((kv & 31) << 1) + ((d >> 3) & 1)) << 3) + (d & 7);
                        qkv[hb + off] = (_Float16)acc[i][j][r];
                    }
                } else {
#pragma unroll
                    for (int r = 0; r < 4; ++r)
                        qkv[(((size_t)b12h << 10) + n + r) * 64 + d] = (_Float16)acc[i][j][r];
                }
            }
        }
    } else {
        float* out = (float*)Cout;
#pragma unroll
        for (int j = 0; j < 4; ++j) {
            const int col = n0 + wn + j * 16 + l15;
            const float bv = bias[col];
#pragma unroll
            for (int i = 0; i < MF; ++i)
#pragma unroll
                for (int r = 0; r < 4; ++r) {
                    const int row = m0 + wm + i * 16 + (l16 << 2) + r;
                    out[(size_t)row * 768 + col] = acc[i][j][r] + bv;
                }
        }
    }
}

// ---------------------------------------------------------------------------
// Flash attention, swapped-operand structure, 32x32x16 MFMA, in-block split-KV,
// single-st cross-segment pipeline, VGPR-dieted for the 64-reg occupancy step:
//  - exp2 done IN PLACE in st (p[] eliminated; st reused by next QK^T after
//    the cvt_pk extraction)
//  - cross-half l-sum deferred to the epilogue (m stays wave-shared, so both
//    halves' l accumulate in the same scale; one shfl at the end)
//  - the 4 fragment shfls issue before QK^T so ds latency hides under MFMA.
// Segment(t): [V(t) loads | softmax(st=S(t)) in place | cvt_pk -> a0..a7 |
//              4 shfl issue | QK^T(t+1)->st | K(t+2) loads | mux build | PV(t)]
__global__ __launch_bounds__(512) void attn_kernel(const _Float16* __restrict__ Qg,
                                                   const _Float16* __restrict__ K4g,
                                                   const _Float16* __restrict__ V4g,
                                                   _Float16* __restrict__ AO) {
    __shared__ float lds_o[4][64][32];      // [wq][lane][32 partial O values]
    __shared__ float2 lds_ml[4][32];        // [wq][q-lane] (m, l)

    const int tid = threadIdx.x, lane = tid & 63, wid = tid >> 6;
    const int l31 = lane & 31, hi = lane >> 5;
    const int wq = wid & 3, kvhalf = wid >> 2;
    const int bh = blockIdx.x;             // b*12+h
    const int q = (blockIdx.y << 7) + (wq << 5) + l31;   // this lane's q row
    const int tbase = kvhalf << 4;         // first 32-kv tile (0 or 16)
    const _Float16* K4h = K4g + ((size_t)bh << 16);  // [32 t][4 kd][64 e][8]
    const _Float16* V4h = V4g + ((size_t)bh << 16);  // [64 vt][64 d][16 kv]

    // Q fragments (B-operand): lane holds Q[q][kd*16 + hi*8 + j]
    f16x8 qf[4];
#pragma unroll
    for (int kd = 0; kd < 4; ++kd)
        qf[kd] = *(const f16x8*)(Qg + (((size_t)bh << 10) + q) * 64 + kd * 16 + hi * 8);

    f32x16 o0, o1;   // O^T acc, d-tiles [0..31],[32..63]: all values belong to q
#pragma unroll
    for (int j = 0; j < 16; ++j) { o0[j] = 0.f; o1[j] = 0.f; }
    float m_run = -INFINITY, l_run = 0.f;   // l_run: OWN half only (summed at end)

    f16x8 kf[4], vf[4];
    f32x16 st;

    // ---- prologue: QK^T of tile tbase into st; kf <- K(tbase+1)
#pragma unroll
    for (int kd = 0; kd < 4; ++kd)
        kf[kd] = *(const f16x8*)(K4h + ((size_t)((tbase << 2) + kd) << 9) +
                                 (((l31 << 1) + hi) << 3));
#pragma unroll
    for (int j = 0; j < 16; ++j) st[j] = 0.f;
#pragma unroll
    for (int kd = 0; kd < 4; ++kd)
        st = __builtin_amdgcn_mfma_f32_32x32x16_f16(kf[kd], qf[kd], st, 0, 0, 0);
#pragma unroll
    for (int kd = 0; kd < 4; ++kd)
        kf[kd] = *(const f16x8*)(K4h + ((size_t)(((tbase + 1) << 2) + kd) << 9) +
                                 (((l31 << 1) + hi) << 3));

#pragma unroll 1
    for (int kt = 0; kt < 16; ++kt) {
        const int tt = tbase + kt;

        // V(t) loads, first in the vmcnt queue for this segment
#pragma unroll
        for (int dh = 0; dh < 2; ++dh)
#pragma unroll
            for (int ks = 0; ks < 2; ++ks)
                vf[dh * 2 + ks] = *(const f16x8*)(V4h + ((size_t)((tt << 1) + ks) << 10) +
                                                  ((dh * 32 + l31) << 4) + hi * 8);

        // ---- softmax on st = S(tile t) (computed one segment ago), IN PLACE
        float tr[8];
#pragma unroll
        for (int j = 0; j < 8; ++j) tr[j] = fmaxf(st[2 * j], st[2 * j + 1]);
#pragma unroll
        for (int j = 0; j < 4; ++j) tr[j] = fmaxf(tr[j], tr[j + 4]);
        float mx = fmaxf(fmaxf(tr[0], tr[2]), fmaxf(tr[1], tr[3]));
        mx = fmaxf(mx, __shfl_xor(mx, 32));   // m shared across halves (required)
        // defer-max (T13): only rescale when the max grew by > 8 (exp2 domain)
        if (!__all(mx <= m_run + 8.f)) {
            const float mnew = fmaxf(m_run, mx);
            const float fac = __builtin_amdgcn_exp2f(m_run - mnew);
            l_run *= fac;
#pragma unroll
            for (int j = 0; j < 16; ++j) { o0[j] *= fac; o1[j] *= fac; }
            m_run = mnew;
        }
#pragma unroll
        for (int j = 0; j < 16; ++j) st[j] = __builtin_amdgcn_exp2f(st[j] - m_run);
        float sr[8];
#pragma unroll
        for (int j = 0; j < 8; ++j) sr[j] = st[2 * j] + st[2 * j + 1];
#pragma unroll
        for (int j = 0; j < 4; ++j) sr[j] = sr[j] + sr[j + 4];
        l_run += (sr[0] + sr[2]) + (sr[1] + sr[3]);   // own half; cross-sum deferred

        // ---- extract PV words from st (st dead after this; a-regs live on)
        const unsigned a0 = pkh(st[0], st[1]),   a1 = pkh(st[2], st[3]);
        const unsigned a2 = pkh(st[4], st[5]),   a3 = pkh(st[6], st[7]);
        const unsigned a4 = pkh(st[8], st[9]),   a5 = pkh(st[10], st[11]);
        const unsigned a6 = pkh(st[12], st[13]), a7 = pkh(st[14], st[15]);
        // issue the 4 cross-half shfls now: ds latency hides under QK^T below
        const unsigned s0 = (unsigned)__shfl_xor((int)(hi ? a0 : a2), 32);
        const unsigned s1 = (unsigned)__shfl_xor((int)(hi ? a1 : a3), 32);
        const unsigned s2 = (unsigned)__shfl_xor((int)(hi ? a4 : a6), 32);
        const unsigned s3 = (unsigned)__shfl_xor((int)(hi ? a5 : a7), 32);

        // ---- QK^T(t+1) -> st (reuse). kf = K(t+1), loaded one segment ago.
#pragma unroll
        for (int j = 0; j < 16; ++j) st[j] = 0.f;
#pragma unroll
        for (int kd = 0; kd < 4; ++kd)
            st = __builtin_amdgcn_mfma_f32_32x32x16_f16(kf[kd], qf[kd], st, 0, 0, 0);

        // kf <- K(t+2) (WAR after QK^T issue; consumed next segment). Wraps.
        const int tn = tbase + ((kt + 2) & 15);
#pragma unroll
        for (int kd = 0; kd < 4; ++kd)
            kf[kd] = *(const f16x8*)(K4h + ((size_t)((tn << 2) + kd) << 9) +
                                     (((l31 << 1) + hi) << 3));
        __builtin_amdgcn_sched_barrier(0);   // all loads issued before the VALU tail

        // ---- build PV B-fragments (mux of own a-words and partner s-words)
        const u32x4 w0 = { hi ? s0 : a0, hi ? s1 : a1, hi ? a2 : s0, hi ? a3 : s1 };
        const u32x4 w1 = { hi ? s2 : a4, hi ? s3 : a5, hi ? a6 : s2, hi ? a7 : s3 };
        const f16x8 pa0 = __builtin_bit_cast(f16x8, w0);  // kv 0..15 slice
        const f16x8 pa1 = __builtin_bit_cast(f16x8, w1);  // kv 16..31 slice

        // O^T[d][q] += sum_kv V[kv][d] * P[q][kv]  (waits vf via vmcnt(4))
        o0 = __builtin_amdgcn_mfma_f32_32x32x16_f16(vf[0], pa0, o0, 0, 0, 0);
        o0 = __builtin_amdgcn_mfma_f32_32x32x16_f16(vf[1], pa1, o0, 0, 0, 0);
        o1 = __builtin_amdgcn_mfma_f32_32x32x16_f16(vf[2], pa0, o1, 0, 0, 0);
        o1 = __builtin_amdgcn_mfma_f32_32x32x16_f16(vf[3], pa1, o1, 0, 0, 0);
    }

    // ---- combine the deferred cross-half l (m is identical for lane pair)
    l_run += __shfl_xor(l_run, 32);

    // ---- in-block split-KV merge ----
    if (kvhalf) {
#pragma unroll
        for (int g = 0; g < 4; ++g) {
            *(f32x4*)&lds_o[wq][lane][4 * g] =
                (f32x4){o0[4 * g + 0], o0[4 * g + 1], o0[4 * g + 2], o0[4 * g + 3]};
            *(f32x4*)&lds_o[wq][lane][16 + 4 * g] =
                (f32x4){o1[4 * g + 0], o1[4 * g + 1], o1[4 * g + 2], o1[4 * g + 3]};
        }
        if (!hi) lds_ml[wq][l31] = make_float2(m_run, l_run);
    }
    __syncthreads();
    if (kvhalf) return;

    // waves 0-3: merge own partial with partner's (same q, same lane mapping)
    const float2 ml2 = lds_ml[wq][l31];
    const float M = fmaxf(m_run, ml2.x);
    const float f1 = __builtin_amdgcn_exp2f(m_run - M);
    const float f2 = __builtin_amdgcn_exp2f(ml2.x - M);
    const float inv = __builtin_amdgcn_rcpf(l_run * f1 + ml2.y * f2);
    const float c1 = f1 * inv, c2 = f2 * inv;

    // epilogue: AO[b][n=q][h*64+d];  d = t*32 + g*8 + hi*4 + i
    const int b = bh / 12, h = bh - (bh / 12) * 12;
    _Float16* dst = AO + ((size_t)b * 1024 + q) * 768 + h * 64 + hi * 4;
#pragma unroll
    for (int g = 0; g < 4; ++g) {
        const f32x4 p0 = *(const f32x4*)&lds_o[wq][lane][4 * g];
        const f32x4 p1 = *(const f32x4*)&lds_o[wq][lane][16 + 4 * g];
        const u32x2 w0 = { pkh(o0[4 * g + 0] * c1 + p0[0] * c2, o0[4 * g + 1] * c1 + p0[1] * c2),
                           pkh(o0[4 * g + 2] * c1 + p0[2] * c2, o0[4 * g + 3] * c1 + p0[3] * c2) };
        *(f16x4*)(dst + g * 8) = __builtin_bit_cast(f16x4, w0);
        const u32x2 w1 = { pkh(o1[4 * g + 0] * c1 + p1[0] * c2, o1[4 * g + 1] * c1 + p1[1] * c2),
                           pkh(o1[4 * g + 2] * c1 + p1[2] * c2, o1[4 * g + 3] * c1 + p1[3] * c2) };
        *(f16x4*)(dst + 32 + g * 8) = __builtin_bit_cast(f16x4, w1);
    }
}

// ---------------------------------------------------------------------------
extern "C" void kernel_launch(void* const* d_in, const int* in_sizes, int n_in,
                              void* d_out, int out_size, void* d_ws, size_t ws_size,
                              hipStream_t stream) {
    (void)in_sizes; (void)n_in; (void)out_size; (void)ws_size;
    const float* x     = (const float*)d_in[0];
    const float* Wqkv  = (const float*)d_in[1];
    const float* Wproj = (const float*)d_in[2];
    const float* bproj = (const float*)d_in[3];
    const float* Aq    = (const float*)d_in[4];
    const float* Bq    = (const float*)d_in[5];
    const float* Av    = (const float*)d_in[6];
    const float* Bv    = (const float*)d_in[7];

    // workspace layout (fp16 elements)
    _Float16* Xb     = (_Float16*)d_ws;          // [8192][768]
    _Float16* Wqkvb  = Xb + 6291456;             // [2304][768]
    _Float16* Wprojb = Wqkvb + 1769472;          // [768][768]
    _Float16* QKV    = Wprojb + 589824;          // Q[96][1024][64] K4[96][...] V4[96][...]
    _Float16* AO     = QKV + 18874368;           // [8192][768]
    float* out = (float*)d_out;

    cast_f32_f16<<<6144, 256, 0, stream>>>(x, Xb, 1572864);
    cast_f32_f16<<<576, 256, 0, stream>>>(Wqkv + 589824, Wqkvb + 589824, 147456);  // K rows
    cast_f32_f16<<<576, 256, 0, stream>>>(Wproj, Wprojb, 147456);
    prep_w<<<dim3(24, 3), 256, 0, stream>>>(Wqkv, Aq, Bq, Av, Bv, Wqkvb);

    // gemm0: grid 64x18 = 1152 blocks (1-D, XCD-swizzled in-kernel)
    gemm_nt<0, 4, 64, 18><<<1152, 256, 0, stream>>>(Xb, Wqkvb, 768, (void*)QKV, nullptr);
    attn_kernel<<<dim3(96, 8), 512, 0, stream>>>(QKV, QKV + 6291456, QKV + 12582912, AO);
    // gemm1: grid 128x6 = 768 blocks (1-D, XCD-swizzled in-kernel)
    gemm_nt<1, 2, 128, 6><<<768, 256, 0, stream>>>(AO, Wprojb, 768, (void*)out, bproj);
}

// Round 12
// 114.413 us; speedup vs baseline: 1.1788x; 1.0639x over previous
//
#include <hip/hip_runtime.h>

#define DEV __device__ __forceinline__

typedef _Float16 f16x8 __attribute__((ext_vector_type(8)));
typedef _Float16 f16x4 __attribute__((ext_vector_type(4)));
typedef float f32x4 __attribute__((ext_vector_type(4)));
typedef float f32x16 __attribute__((ext_vector_type(16)));
typedef unsigned int u32x4 __attribute__((ext_vector_type(4)));
typedef unsigned int u32x2 __attribute__((ext_vector_type(2)));

// async global->LDS, 16B per lane. LDS dest must be wave-uniform base (+lane*16 in HW).
DEV void glds16(const void* g, void* l) {
    __builtin_amdgcn_global_load_lds(
        (const __attribute__((address_space(1))) void*)g,
        (__attribute__((address_space(3))) void*)l, 16, 0, 0);
}

DEV unsigned pkh(float lo, float hi) {
    return __builtin_bit_cast(unsigned, __builtin_amdgcn_cvt_pkrtz(lo, hi));
}

// ---------------------------------------------------------------------------
// ONE prep kernel (was 3 casts + prep_w = 4 launches):
//   blk [0,72):        LoRA fold into Q/V rows of Wqkvb (+ scale*log2e on Q)
//   blk [72,6216):     x cast fp32->fp16 (6144 blocks)
//   blk [6216,6792):   Wqkv K-rows cast (576)
//   blk [6792,7368):   Wproj cast (576)
// Heavy blocks first so the tail is the cheap casts. All regions independent.
__global__ __launch_bounds__(256) void prep_all(const float* __restrict__ x,
                                                const float* __restrict__ Wqkv,
                                                const float* __restrict__ Wproj,
                                                const float* __restrict__ Aq,
                                                const float* __restrict__ Bq,
                                                const float* __restrict__ Av,
                                                const float* __restrict__ Bv,
                                                _Float16* __restrict__ Xb,
                                                _Float16* __restrict__ Wqkvb,
                                                _Float16* __restrict__ Wprojb) {
    const int blk = blockIdx.x;
    if (blk < 72) {
        // LoRA fold: 24 (sec,head) x 3 column-chunks
        const int bx = blk % 24, cy = blk / 24;
        const int sec = bx / 12;           // 0 = Q, 1 = V
        const int h = bx - sec * 12;
        const float* Am = sec ? Av : Aq;   // [64][4]
        const float* Bm = sec ? Bv : Bq;   // [4][64]
        const int base = sec ? (1536 + h * 64) : (h * 64);
        const float scale = sec ? 1.0f : (0.125f * 1.4426950408889634f);
        const int c = cy * 256 + threadIdx.x;
        float t0 = 0.f, t1 = 0.f, t2 = 0.f, t3 = 0.f;
        for (int j = 0; j < 64; ++j) {
            const float w = Wqkv[(size_t)(base + j) * 768 + c];
            t0 += Am[j * 4 + 0] * w;
            t1 += Am[j * 4 + 1] * w;
            t2 += Am[j * 4 + 2] * w;
            t3 += Am[j * 4 + 3] * w;
        }
        for (int i = 0; i < 64; ++i) {
            const float w = Wqkv[(size_t)(base + i) * 768 + c];
            const float val = w + t0 * Bm[i] + t1 * Bm[64 + i] + t2 * Bm[128 + i] + t3 * Bm[192 + i];
            Wqkvb[(size_t)(base + i) * 768 + c] = (_Float16)(val * scale);
        }
        return;
    }
    const float* src;
    _Float16* dst;
    int i;
    if (blk < 6216) {          // x cast
        i = (blk - 72) * 256 + threadIdx.x;
        src = x; dst = Xb;
    } else if (blk < 6792) {   // Wqkv K-rows cast
        i = (blk - 6216) * 256 + threadIdx.x;
        src = Wqkv + 589824; dst = Wqkvb + 589824;
    } else {                   // Wproj cast
        i = (blk - 6792) * 256 + threadIdx.x;
        src = Wproj; dst = Wprojb;
    }
    const float4 v = ((const float4*)src)[i];
    f16x4 o = { (_Float16)v.x, (_Float16)v.y, (_Float16)v.z, (_Float16)v.w };
    *(f16x4*)(dst + (size_t)i * 4) = o;
}

// ---------------------------------------------------------------------------
// BMx128 NT GEMM (BM = MF*32), BK=64, 4 waves (2x2), fp16 in / fp32 acc.
// Pipeline per K-step: ds_read ALL frags -> regs; barrier (LDS free); issue
// async stage of tile t+1 (global_load_lds); MFMAs from regs overlap the DMA;
// barrier (drains vmcnt) -> next iter reads the fresh tile. Single LDS buffer.
// 1-D grid with XCD-chunked swizzle.
// EPI 0 (MF=4): scatter into Q[96][1024][64], K4[96][kv/32][4][64][8],
//               V4[96][kv/16][64][16].
// EPI 1 (MF=2): +bias, fp32 out [M][768].
template <int EPI, int MF, int GX, int GY>
__global__ __launch_bounds__(256) void gemm_nt(const _Float16* __restrict__ A,
                                               const _Float16* __restrict__ B,
                                               int Kdim, void* __restrict__ Cout,
                                               const float* __restrict__ bias) {
    constexpr int BM = MF * 32;
    constexpr int XB = GX / 8;   // M-panels per XCD chunk
    __shared__ __align__(16) _Float16 As[BM * 64];
    __shared__ __align__(16) _Float16 Bs[128 * 64];
    const int tid = threadIdx.x;
    const int lane = tid & 63, wid = tid >> 6;
    const int l15 = lane & 15, l16 = lane >> 4;
    // XCD-chunked swizzle (bijective: GX*GY % 8 == 0, XB integral)
    const int id = blockIdx.x;
    const int xcd = id & 7, c = id >> 3;          // c in [0, GX*GY/8)
    const int bx = xcd * XB + (c % XB), by = c / XB;
    const int m0 = bx * BM, n0 = by << 7;
    const int wm = (wid >> 1) * (MF * 16), wn = (wid & 1) << 6;

    auto stage = [&](int k0) {
#pragma unroll
        for (int rr = 0; rr < MF; ++rr) {
            const int slot = (rr << 8) + tid;
            const int row = slot >> 3, sl = slot & 7;
            glds16(A + (size_t)(m0 + row) * Kdim + k0 + ((sl ^ (row & 7)) << 3),
                   (char*)As + (((rr << 8) + (wid << 6)) << 4));
        }
#pragma unroll
        for (int rr = 0; rr < 4; ++rr) {
            const int slot = (rr << 8) + tid;
            const int row = slot >> 3, sl = slot & 7;
            glds16(B + (size_t)(n0 + row) * Kdim + k0 + ((sl ^ (row & 7)) << 3),
                   (char*)Bs + (((rr << 8) + (wid << 6)) << 4));
        }
    };

    f32x4 acc[MF][4];
#pragma unroll
    for (int i = 0; i < MF; ++i)
#pragma unroll
        for (int j = 0; j < 4; ++j) acc[i][j] = (f32x4){0.f, 0.f, 0.f, 0.f};

    stage(0);
    __syncthreads();   // tile 0 landed (vmcnt drained by barrier semantics)

    for (int k0 = 0; k0 < Kdim; k0 += 64) {
        // read ALL fragments of this tile into registers
        f16x8 af[2][MF], bf[2][4];
#pragma unroll
        for (int kh = 0; kh < 2; ++kh) {
#pragma unroll
            for (int i = 0; i < MF; ++i) {
                const int ra = wm + i * 16 + l15;
                af[kh][i] = *(const f16x8*)((const char*)As + ra * 128 +
                                            ((((kh << 2) + l16) ^ (ra & 7)) << 4));
            }
#pragma unroll
            for (int j = 0; j < 4; ++j) {
                const int rb = wn + j * 16 + l15;
                bf[kh][j] = *(const f16x8*)((const char*)Bs + rb * 128 +
                                            ((((kh << 2) + l16) ^ (rb & 7)) << 4));
            }
        }
        __syncthreads();   // all LDS reads done -> buffer free for overwrite
        if (k0 + 64 < Kdim) stage(k0 + 64);   // async DMA of next tile
        __builtin_amdgcn_sched_barrier(0);    // keep MFMAs after stage issue
#pragma unroll
        for (int kh = 0; kh < 2; ++kh)
#pragma unroll
            for (int i = 0; i < MF; ++i)
#pragma unroll
                for (int j = 0; j < 4; ++j)
                    acc[i][j] = __builtin_amdgcn_mfma_f32_16x16x32_f16(af[kh][i], bf[kh][j],
                                                                       acc[i][j], 0, 0, 0);
        __syncthreads();   // staged tile landed (vmcnt drained)
    }

    if (EPI == 0) {
        _Float16* qkv = (_Float16*)Cout;
#pragma unroll
        for (int j = 0; j < 4; ++j) {
            const int col = n0 + wn + j * 16 + l15;   // 0..2303 = [3][12][64]
            const int which = col / 768;
            const int rem = col - which * 768;
            const int hh = rem >> 6, d = rem & 63;
#pragma unroll
            for (int i = 0; i < MF; ++i) {
                const int rowb = m0 + wm + i * 16 + (l16 << 2);  // b*1024+n, 4-aligned
                const int b = rowb >> 10, n = rowb & 1023;
                const int b12h = b * 12 + hh;
                if (which == 2) {
                    // V4[bh][n>>4][d][n&15]: 4 consecutive kv -> 8B store
                    f16x4 pk = { (_Float16)acc[i][j][0], (_Float16)acc[i][j][1],
                                 (_Float16)acc[i][j][2], (_Float16)acc[i][j][3] };
                    *(f16x4*)(qkv + 12582912 +
                              ((((size_t)b12h * 64 + (n >> 4)) * 64 + d) << 4) + (n & 15)) = pk;
                } else if (which == 1) {
                    // K4[bh][kv>>5][d>>4][(kv&31)*2 + ((d>>3)&1)][d&7]
                    const size_t hb = 6291456 + ((size_t)b12h << 16);
#pragma unroll
                    for (int r = 0; r < 4; ++r) {
                        const int kv = n + r;
                        const int off = ((((kv >> 5) << 2) + (d >> 4)) << 9) +
                                        ((((kv & 31) << 1) + ((d >> 3) & 1)) << 3) + (d & 7);
                        qkv[hb + off] = (_Float16)acc[i][j][r];
                    }
                } else {
#pragma unroll
                    for (int r = 0; r < 4; ++r)
                        qkv[(((size_t)b12h << 10) + n + r) * 64 + d] = (_Float16)acc[i][j][r];
                }
            }
        }
    } else {
        float* out = (float*)Cout;
#pragma unroll
        for (int j = 0; j < 4; ++j) {
            const int col = n0 + wn + j * 16 + l15;
            const float bv = bias[col];
#pragma unroll
            for (int i = 0; i < MF; ++i)
#pragma unroll
                for (int r = 0; r < 4; ++r) {
                    const int row = m0 + wm + i * 16 + (l16 << 2) + r;
                    out[(size_t)row * 768 + col] = acc[i][j][r] + bv;
                }
        }
    }
}

// ---------------------------------------------------------------------------
// Flash attention, swapped-operand structure, 32x32x16 MFMA, in-block split-KV,
// single-st cross-segment pipeline, VGPR<=64 (8 waves/SIMD band).
// This round: s_setprio(1) around both MFMA clusters (T5 -- waves are
// barrier-free and phase-diverse, m191's +4-7% regime) and max3-style reduce
// tree (T17: 3-ary fmaxf chains fuse to v_max3_f32; 15 ops/depth4 -> 8/depth3).
__global__ __launch_bounds__(512) void attn_kernel(const _Float16* __restrict__ Qg,
                                                   const _Float16* __restrict__ K4g,
                                                   const _Float16* __restrict__ V4g,
                                                   _Float16* __restrict__ AO) {
    __shared__ float lds_o[4][64][32];      // [wq][lane][32 partial O values]
    __shared__ float2 lds_ml[4][32];        // [wq][q-lane] (m, l)

    const int tid = threadIdx.x, lane = tid & 63, wid = tid >> 6;
    const int l31 = lane & 31, hi = lane >> 5;
    const int wq = wid & 3, kvhalf = wid >> 2;
    const int bh = blockIdx.x;             // b*12+h
    const int q = (blockIdx.y << 7) + (wq << 5) + l31;   // this lane's q row
    const int tbase = kvhalf << 4;         // first 32-kv tile (0 or 16)
    const _Float16* K4h = K4g + ((size_t)bh << 16);  // [32 t][4 kd][64 e][8]
    const _Float16* V4h = V4g + ((size_t)bh << 16);  // [64 vt][64 d][16 kv]

    // Q fragments (B-operand): lane holds Q[q][kd*16 + hi*8 + j]
    f16x8 qf[4];
#pragma unroll
    for (int kd = 0; kd < 4; ++kd)
        qf[kd] = *(const f16x8*)(Qg + (((size_t)bh << 10) + q) * 64 + kd * 16 + hi * 8);

    f32x16 o0, o1;   // O^T acc, d-tiles [0..31],[32..63]: all values belong to q
#pragma unroll
    for (int j = 0; j < 16; ++j) { o0[j] = 0.f; o1[j] = 0.f; }
    float m_run = -INFINITY, l_run = 0.f;   // l_run: OWN half only (summed at end)

    f16x8 kf[4], vf[4];
    f32x16 st;

    // ---- prologue: QK^T of tile tbase into st; kf <- K(tbase+1)
#pragma unroll
    for (int kd = 0; kd < 4; ++kd)
        kf[kd] = *(const f16x8*)(K4h + ((size_t)((tbase << 2) + kd) << 9) +
                                 (((l31 << 1) + hi) << 3));
#pragma unroll
    for (int j = 0; j < 16; ++j) st[j] = 0.f;
#pragma unroll
    for (int kd = 0; kd < 4; ++kd)
        st = __builtin_amdgcn_mfma_f32_32x32x16_f16(kf[kd], qf[kd], st, 0, 0, 0);
#pragma unroll
    for (int kd = 0; kd < 4; ++kd)
        kf[kd] = *(const f16x8*)(K4h + ((size_t)(((tbase + 1) << 2) + kd) << 9) +
                                 (((l31 << 1) + hi) << 3));

#pragma unroll 1
    for (int kt = 0; kt < 16; ++kt) {
        const int tt = tbase + kt;

        // V(t) loads, first in the vmcnt queue for this segment
#pragma unroll
        for (int dh = 0; dh < 2; ++dh)
#pragma unroll
            for (int ks = 0; ks < 2; ++ks)
                vf[dh * 2 + ks] = *(const f16x8*)(V4h + ((size_t)((tt << 1) + ks) << 10) +
                                                  ((dh * 32 + l31) << 4) + hi * 8);

        // ---- softmax on st = S(tile t) (computed one segment ago), IN PLACE
        // max3-friendly 3-ary tree (8 ops, depth 3)
        const float g0 = fmaxf(fmaxf(st[0], st[1]), st[2]);
        const float g1 = fmaxf(fmaxf(st[3], st[4]), st[5]);
        const float g2 = fmaxf(fmaxf(st[6], st[7]), st[8]);
        const float g3 = fmaxf(fmaxf(st[9], st[10]), st[11]);
        const float g4 = fmaxf(fmaxf(st[12], st[13]), st[14]);
        float mx = fmaxf(fmaxf(fmaxf(g0, g1), g2), fmaxf(fmaxf(g3, g4), st[15]));
        mx = fmaxf(mx, __shfl_xor(mx, 32));   // m shared across halves (required)
        // defer-max (T13): only rescale when the max grew by > 8 (exp2 domain)
        if (!__all(mx <= m_run + 8.f)) {
            const float mnew = fmaxf(m_run, mx);
            const float fac = __builtin_amdgcn_exp2f(m_run - mnew);
            l_run *= fac;
#pragma unroll
            for (int j = 0; j < 16; ++j) { o0[j] *= fac; o1[j] *= fac; }
            m_run = mnew;
        }
#pragma unroll
        for (int j = 0; j < 16; ++j) st[j] = __builtin_amdgcn_exp2f(st[j] - m_run);
        float sr[8];
#pragma unroll
        for (int j = 0; j < 8; ++j) sr[j] = st[2 * j] + st[2 * j + 1];
#pragma unroll
        for (int j = 0; j < 4; ++j) sr[j] = sr[j] + sr[j + 4];
        l_run += (sr[0] + sr[2]) + (sr[1] + sr[3]);   // own half; cross-sum deferred

        // ---- extract PV words from st (st dead after this; a-regs live on)
        const unsigned a0 = pkh(st[0], st[1]),   a1 = pkh(st[2], st[3]);
        const unsigned a2 = pkh(st[4], st[5]),   a3 = pkh(st[6], st[7]);
        const unsigned a4 = pkh(st[8], st[9]),   a5 = pkh(st[10], st[11]);
        const unsigned a6 = pkh(st[12], st[13]), a7 = pkh(st[14], st[15]);
        // issue the 4 cross-half shfls now: ds latency hides under QK^T below
        const unsigned s0 = (unsigned)__shfl_xor((int)(hi ? a0 : a2), 32);
        const unsigned s1 = (unsigned)__shfl_xor((int)(hi ? a1 : a3), 32);
        const unsigned s2 = (unsigned)__shfl_xor((int)(hi ? a4 : a6), 32);
        const unsigned s3 = (unsigned)__shfl_xor((int)(hi ? a5 : a7), 32);

        // ---- QK^T(t+1) -> st (reuse). kf = K(t+1), loaded one segment ago.
#pragma unroll
        for (int j = 0; j < 16; ++j) st[j] = 0.f;
        __builtin_amdgcn_s_setprio(1);
#pragma unroll
        for (int kd = 0; kd < 4; ++kd)
            st = __builtin_amdgcn_mfma_f32_32x32x16_f16(kf[kd], qf[kd], st, 0, 0, 0);
        __builtin_amdgcn_s_setprio(0);

        // kf <- K(t+2) (WAR after QK^T issue; consumed next segment). Wraps.
        const int tn = tbase + ((kt + 2) & 15);
#pragma unroll
        for (int kd = 0; kd < 4; ++kd)
            kf[kd] = *(const f16x8*)(K4h + ((size_t)((tn << 2) + kd) << 9) +
                                     (((l31 << 1) + hi) << 3));
        __builtin_amdgcn_sched_barrier(0);   // all loads issued before the VALU tail

        // ---- build PV B-fragments (mux of own a-words and partner s-words)
        const u32x4 w0 = { hi ? s0 : a0, hi ? s1 : a1, hi ? a2 : s0, hi ? a3 : s1 };
        const u32x4 w1 = { hi ? s2 : a4, hi ? s3 : a5, hi ? a6 : s2, hi ? a7 : s3 };
        const f16x8 pa0 = __builtin_bit_cast(f16x8, w0);  // kv 0..15 slice
        const f16x8 pa1 = __builtin_bit_cast(f16x8, w1);  // kv 16..31 slice

        // O^T[d][q] += sum_kv V[kv][d] * P[q][kv]  (waits vf via vmcnt(4))
        __builtin_amdgcn_s_setprio(1);
        o0 = __builtin_amdgcn_mfma_f32_32x32x16_f16(vf[0], pa0, o0, 0, 0, 0);
        o0 = __builtin_amdgcn_mfma_f32_32x32x16_f16(vf[1], pa1, o0, 0, 0, 0);
        o1 = __builtin_amdgcn_mfma_f32_32x32x16_f16(vf[2], pa0, o1, 0, 0, 0);
        o1 = __builtin_amdgcn_mfma_f32_32x32x16_f16(vf[3], pa1, o1, 0, 0, 0);
        __builtin_amdgcn_s_setprio(0);
    }

    // ---- combine the deferred cross-half l (m is identical for lane pair)
    l_run += __shfl_xor(l_run, 32);

    // ---- in-block split-KV merge ----
    if (kvhalf) {
#pragma unroll
        for (int g = 0; g < 4; ++g) {
            *(f32x4*)&lds_o[wq][lane][4 * g] =
                (f32x4){o0[4 * g + 0], o0[4 * g + 1], o0[4 * g + 2], o0[4 * g + 3]};
            *(f32x4*)&lds_o[wq][lane][16 + 4 * g] =
                (f32x4){o1[4 * g + 0], o1[4 * g + 1], o1[4 * g + 2], o1[4 * g + 3]};
        }
        if (!hi) lds_ml[wq][l31] = make_float2(m_run, l_run);
    }
    __syncthreads();
    if (kvhalf) return;

    // waves 0-3: merge own partial with partner's (same q, same lane mapping)
    const float2 ml2 = lds_ml[wq][l31];
    const float M = fmaxf(m_run, ml2.x);
    const float f1 = __builtin_amdgcn_exp2f(m_run - M);
    const float f2 = __builtin_amdgcn_exp2f(ml2.x - M);
    const float inv = __builtin_amdgcn_rcpf(l_run * f1 + ml2.y * f2);
    const float c1 = f1 * inv, c2 = f2 * inv;

    // epilogue: AO[b][n=q][h*64+d];  d = t*32 + g*8 + hi*4 + i
    const int b = bh / 12, h = bh - (bh / 12) * 12;
    _Float16* dst = AO + ((size_t)b * 1024 + q) * 768 + h * 64 + hi * 4;
#pragma unroll
    for (int g = 0; g < 4; ++g) {
        const f32x4 p0 = *(const f32x4*)&lds_o[wq][lane][4 * g];
        const f32x4 p1 = *(const f32x4*)&lds_o[wq][lane][16 + 4 * g];
        const u32x2 w0 = { pkh(o0[4 * g + 0] * c1 + p0[0] * c2, o0[4 * g + 1] * c1 + p0[1] * c2),
                           pkh(o0[4 * g + 2] * c1 + p0[2] * c2, o0[4 * g + 3] * c1 + p0[3] * c2) };
        *(f16x4*)(dst + g * 8) = __builtin_bit_cast(f16x4, w0);
        const u32x2 w1 = { pkh(o1[4 * g + 0] * c1 + p1[0] * c2, o1[4 * g + 1] * c1 + p1[1] * c2),
                           pkh(o1[4 * g + 2] * c1 + p1[2] * c2, o1[4 * g + 3] * c1 + p1[3] * c2) };
        *(f16x4*)(dst + 32 + g * 8) = __builtin_bit_cast(f16x4, w1);
    }
}

// ---------------------------------------------------------------------------
extern "C" void kernel_launch(void* const* d_in, const int* in_sizes, int n_in,
                              void* d_out, int out_size, void* d_ws, size_t ws_size,
                              hipStream_t stream) {
    (void)in_sizes; (void)n_in; (void)out_size; (void)ws_size;
    const float* x     = (const float*)d_in[0];
    const float* Wqkv  = (const float*)d_in[1];
    const float* Wproj = (const float*)d_in[2];
    const float* bproj = (const float*)d_in[3];
    const float* Aq    = (const float*)d_in[4];
    const float* Bq    = (const float*)d_in[5];
    const float* Av    = (const float*)d_in[6];
    const float* Bv    = (const float*)d_in[7];

    // workspace layout (fp16 elements)
    _Float16* Xb     = (_Float16*)d_ws;          // [8192][768]
    _Float16* Wqkvb  = Xb + 6291456;             // [2304][768]
    _Float16* Wprojb = Wqkvb + 1769472;          // [768][768]
    _Float16* QKV    = Wprojb + 589824;          // Q[96][1024][64] K4[96][...] V4[96][...]
    _Float16* AO     = QKV + 18874368;           // [8192][768]
    float* out = (float*)d_out;

    // single prep launch: LoRA fold (72 blocks) + x cast (6144) + 2 weight casts
    prep_all<<<7368, 256, 0, stream>>>(x, Wqkv, Wproj, Aq, Bq, Av, Bv,
                                       Xb, Wqkvb, Wprojb);

    // gemm0: grid 64x18 = 1152 blocks (1-D, XCD-swizzled in-kernel)
    gemm_nt<0, 4, 64, 18><<<1152, 256, 0, stream>>>(Xb, Wqkvb, 768, (void*)QKV, nullptr);
    attn_kernel<<<dim3(96, 8), 512, 0, stream>>>(QKV, QKV + 6291456, QKV + 12582912, AO);
    // gemm1: grid 128x6 = 768 blocks (1-D, XCD-swizzled in-kernel)
    gemm_nt<1, 2, 128, 6><<<768, 256, 0, stream>>>(AO, Wprojb, 768, (void*)out, bproj);
}